// Round 1
// baseline (253.679 us; speedup 1.0000x reference)
//
#include <hip/hip_runtime.h>
#include <hip/hip_bf16.h>
#include <math.h>

// B=2, S=160, H=768, C=5 ; M = B*S = 320, N = C*H = 3840, K = H = 768

__global__ __launch_bounds__(256) void proj_gemm(
    const float* __restrict__ A,     // [320, 768]
    const float* __restrict__ Wp,    // [768, 3840]
    const float* __restrict__ bp,    // [3840]
    const float* __restrict__ Wa,
    const float* __restrict__ ba,
    float* __restrict__ hp,          // [320, 3840]
    float* __restrict__ ha)
{
    const int which = blockIdx.z;
    const float* W    = which ? Wa : Wp;
    const float* bias = which ? ba : bp;
    float* out        = which ? ha : hp;

    const int n0 = blockIdx.x * 64;
    const int m0 = blockIdx.y * 64;
    const int tid = threadIdx.x;
    const int tx = tid & 15, ty = tid >> 4;

    __shared__ __attribute__((aligned(16))) float As[16][64];
    __shared__ __attribute__((aligned(16))) float Bs[16][64];

    float acc[4][4] = {};

    for (int k0 = 0; k0 < 768; k0 += 16) {
        {   // A tile 64x16 -> As[k][m] (transposed store)
            const int r  = tid >> 2;
            const int kk = (tid & 3) * 4;
            float4 a4 = *reinterpret_cast<const float4*>(&A[(m0 + r) * 768 + k0 + kk]);
            As[kk + 0][r] = a4.x;
            As[kk + 1][r] = a4.y;
            As[kk + 2][r] = a4.z;
            As[kk + 3][r] = a4.w;
        }
        {   // B tile 16x64
            const int k  = tid >> 4;
            const int cc = (tid & 15) * 4;
            *reinterpret_cast<float4*>(&Bs[k][cc]) =
                *reinterpret_cast<const float4*>(&W[(size_t)(k0 + k) * 3840 + n0 + cc]);
        }
        __syncthreads();
        #pragma unroll
        for (int k = 0; k < 16; ++k) {
            float4 a4 = *reinterpret_cast<const float4*>(&As[k][ty * 4]);
            float4 b4 = *reinterpret_cast<const float4*>(&Bs[k][tx * 4]);
            float av[4] = {a4.x, a4.y, a4.z, a4.w};
            float bv[4] = {b4.x, b4.y, b4.z, b4.w};
            #pragma unroll
            for (int i = 0; i < 4; ++i)
                #pragma unroll
                for (int j = 0; j < 4; ++j)
                    acc[i][j] = fmaf(av[i], bv[j], acc[i][j]);
        }
        __syncthreads();
    }

    float4 b4 = *reinterpret_cast<const float4*>(&bias[n0 + tx * 4]);
    float bb[4] = {b4.x, b4.y, b4.z, b4.w};
    #pragma unroll
    for (int i = 0; i < 4; ++i) {
        float4 o;
        o.x = acc[i][0] + bb[0];
        o.y = acc[i][1] + bb[1];
        o.z = acc[i][2] + bb[2];
        o.w = acc[i][3] + bb[3];
        *reinterpret_cast<float4*>(&out[(size_t)(m0 + ty * 4 + i) * 3840 + n0 + tx * 4]) = o;
    }
}

// score[b,p,c,a] = sum_h tanh(hp[b,p,c,h] + ha[b,a,c,h]) * w_out[h]  + mask bias
__global__ __launch_bounds__(256) void scores_kernel(
    const float* __restrict__ hp,    // [320, 3840]
    const float* __restrict__ ha,    // [320, 3840]
    const float* __restrict__ w_out, // [768]
    const int*  __restrict__ mask,   // [B,S,C,S] as int32
    float* __restrict__ out)         // [B,S,C,S]
{
    const int at = blockIdx.x;       // 0..9
    const int pt = blockIdx.y;       // 0..9
    const int bc = blockIdx.z;       // 0..9
    const int b = bc / 5, c = bc % 5;

    const int tid = threadIdx.x;
    const int tp = tid >> 4, ta = tid & 15;

    __shared__ __attribute__((aligned(16))) float w_s[768];
    __shared__ __attribute__((aligned(16))) float hp_s[16][260]; // 256 + 4 pad
    __shared__ __attribute__((aligned(16))) float ha_s[16][260];

    if (tid < 192) {
        *reinterpret_cast<float4*>(&w_s[tid * 4]) =
            *reinterpret_cast<const float4*>(&w_out[tid * 4]);
    }

    const float* hp_base = hp + (size_t)(b * 160 + pt * 16) * 3840 + c * 768;
    const float* ha_base = ha + (size_t)(b * 160 + at * 16) * 3840 + c * 768;

    float acc = 0.f;

    for (int k0 = 0; k0 < 768; k0 += 256) {
        __syncthreads();   // protects w_s (iter 0) and hp_s/ha_s reuse (iters 1,2)
        #pragma unroll
        for (int i = 0; i < 4; ++i) {
            int f4  = i * 256 + tid;       // 0..1023
            int row = f4 >> 6;             // 16 rows, 64 float4 each
            int col = (f4 & 63) * 4;
            *reinterpret_cast<float4*>(&hp_s[row][col]) =
                *reinterpret_cast<const float4*>(&hp_base[(size_t)row * 3840 + k0 + col]);
            *reinterpret_cast<float4*>(&ha_s[row][col]) =
                *reinterpret_cast<const float4*>(&ha_base[(size_t)row * 3840 + k0 + col]);
        }
        __syncthreads();
        #pragma unroll 4
        for (int j = 0; j < 64; ++j) {
            float4 p4 = *reinterpret_cast<const float4*>(&hp_s[tp][j * 4]);
            float4 a4 = *reinterpret_cast<const float4*>(&ha_s[ta][j * 4]);
            float4 w4 = *reinterpret_cast<const float4*>(&w_s[k0 + j * 4]);
            acc = fmaf(tanhf(p4.x + a4.x), w4.x, acc);
            acc = fmaf(tanhf(p4.y + a4.y), w4.y, acc);
            acc = fmaf(tanhf(p4.z + a4.z), w4.z, acc);
            acc = fmaf(tanhf(p4.w + a4.w), w4.w, acc);
        }
    }

    const int p = pt * 16 + tp;
    const int a = at * 16 + ta;
    const size_t idx = ((size_t)(b * 160 + p) * 5 + c) * 160 + a;
    out[idx] = acc + (mask[idx] ? 0.f : -1024.f);
}

// one wave per (b,p,c) row of 160 args
__global__ __launch_bounds__(256) void loss_kernel(
    const float* __restrict__ scores,  // [1600,160]
    const int*  __restrict__ target,
    float* __restrict__ acc)           // acc[0]=sum(-logsm*t), acc[1]=sum(t)
{
    const int lane = threadIdx.x & 63;
    const int wid  = threadIdx.x >> 6;
    const int row  = blockIdx.x * 4 + wid;  // 0..1599
    const float* x = scores + (size_t)row * 160;
    const int*  t  = target + (size_t)row * 160;

    float x0 = x[lane];
    float x1 = x[lane + 64];
    float x2 = (lane < 32) ? x[lane + 128] : -INFINITY;

    float m = fmaxf(fmaxf(x0, x1), x2);
    #pragma unroll
    for (int o = 32; o >= 1; o >>= 1)
        m = fmaxf(m, __shfl_xor(m, o));

    float s = __expf(x0 - m) + __expf(x1 - m) + ((lane < 32) ? __expf(x2 - m) : 0.f);
    #pragma unroll
    for (int o = 32; o >= 1; o >>= 1)
        s += __shfl_xor(s, o);
    float lse = logf(s) + m;

    int t0 = t[lane], t1 = t[lane + 64];
    int t2 = (lane < 32) ? t[lane + 128] : 0;
    float pl = (float)t0 * (lse - x0) + (float)t1 * (lse - x1)
             + ((lane < 32 && t2) ? (float)t2 * (lse - x2) : 0.f);
    float pts = (float)(t0 + t1 + t2);
    #pragma unroll
    for (int o = 32; o >= 1; o >>= 1) {
        pl  += __shfl_xor(pl, o);
        pts += __shfl_xor(pts, o);
    }
    if (lane == 0) {
        atomicAdd(&acc[0], pl);
        atomicAdd(&acc[1], pts);
    }
}

__global__ void finalize_kernel(const float* __restrict__ acc, float* __restrict__ out0)
{
    out0[0] = acc[0] / (acc[1] + 1e-6f);
}

extern "C" void kernel_launch(void* const* d_in, const int* in_sizes, int n_in,
                              void* d_out, int out_size, void* d_ws, size_t ws_size,
                              hipStream_t stream) {
    const float* seq   = (const float*)d_in[0];
    const float* w_prd = (const float*)d_in[1];
    const float* b_prd = (const float*)d_in[2];
    const float* w_arg = (const float*)d_in[3];
    const float* b_arg = (const float*)d_in[4];
    const float* w_out = (const float*)d_in[5];
    const int*   mask  = (const int*)d_in[6];
    const int*   targ  = (const int*)d_in[7];

    float* out = (float*)d_out;          // out[0]=loss, out+1 = scores [2,160,5,160]
    float* hp  = (float*)d_ws;           // [320,3840]
    float* ha  = hp + 320 * 3840;        // [320,3840]
    float* acc = ha + 320 * 3840;        // [2]

    hipMemsetAsync(acc, 0, 2 * sizeof(float), stream);

    dim3 g1(60, 5, 2);   // N/64, M/64, {prd,arg}
    proj_gemm<<<g1, 256, 0, stream>>>(seq, w_prd, b_prd, w_arg, b_arg, hp, ha);

    dim3 g2(10, 10, 10); // a-tiles, p-tiles, b*c
    scores_kernel<<<g2, 256, 0, stream>>>(hp, ha, w_out, mask, out + 1);

    loss_kernel<<<400, 256, 0, stream>>>(out + 1, targ, acc);
    finalize_kernel<<<1, 1, 0, stream>>>(acc, out);
}

// Round 2
// 181.999 us; speedup vs baseline: 1.3938x; 1.3938x over previous
//
#include <hip/hip_runtime.h>
#include <hip/hip_bf16.h>
#include <math.h>

// B=2, S=160, H=768, C=5 ; M = B*S = 320, N = C*H = 3840, K = H = 768

__device__ __forceinline__ float fast_tanh(float x) {
    // clamp to [-4,4]; odd Pade (945+105x^2+x^4)/(945+420x^2+15x^4), err <~2e-3
    x = __builtin_amdgcn_fmed3f(x, -4.0f, 4.0f);
    float x2  = x * x;
    float num = x * fmaf(x2, x2 + 105.f, 945.f);
    float den = fmaf(x2, fmaf(x2, 15.f, 420.f), 945.f);
    return num * __builtin_amdgcn_rcpf(den);
}

__global__ __launch_bounds__(256) void proj_gemm(
    const float* __restrict__ A,     // [320, 768]
    const float* __restrict__ Wp,    // [768, 3840]
    const float* __restrict__ bp,    // [3840]
    const float* __restrict__ Wa,
    const float* __restrict__ ba,
    float* __restrict__ hp,          // [320, 3840]
    float* __restrict__ ha)
{
    const int which = blockIdx.z;
    const float* W    = which ? Wa : Wp;
    const float* bias = which ? ba : bp;
    float* out        = which ? ha : hp;

    const int n0 = blockIdx.x * 64;
    const int m0 = blockIdx.y * 64;
    const int tid = threadIdx.x;
    const int tx = tid & 15, ty = tid >> 4;

    __shared__ __attribute__((aligned(16))) float As[16][64];
    __shared__ __attribute__((aligned(16))) float Bs[16][64];

    float acc[4][4] = {};

    for (int k0 = 0; k0 < 768; k0 += 16) {
        {   // A tile 64x16 -> As[k][m] (transposed store)
            const int r  = tid >> 2;
            const int kk = (tid & 3) * 4;
            float4 a4 = *reinterpret_cast<const float4*>(&A[(m0 + r) * 768 + k0 + kk]);
            As[kk + 0][r] = a4.x;
            As[kk + 1][r] = a4.y;
            As[kk + 2][r] = a4.z;
            As[kk + 3][r] = a4.w;
        }
        {   // B tile 16x64
            const int k  = tid >> 4;
            const int cc = (tid & 15) * 4;
            *reinterpret_cast<float4*>(&Bs[k][cc]) =
                *reinterpret_cast<const float4*>(&W[(size_t)(k0 + k) * 3840 + n0 + cc]);
        }
        __syncthreads();
        #pragma unroll
        for (int k = 0; k < 16; ++k) {
            float4 a4 = *reinterpret_cast<const float4*>(&As[k][ty * 4]);
            float4 b4 = *reinterpret_cast<const float4*>(&Bs[k][tx * 4]);
            float av[4] = {a4.x, a4.y, a4.z, a4.w};
            float bv[4] = {b4.x, b4.y, b4.z, b4.w};
            #pragma unroll
            for (int i = 0; i < 4; ++i)
                #pragma unroll
                for (int j = 0; j < 4; ++j)
                    acc[i][j] = fmaf(av[i], bv[j], acc[i][j]);
        }
        __syncthreads();
    }

    float4 b4 = *reinterpret_cast<const float4*>(&bias[n0 + tx * 4]);
    float bb[4] = {b4.x, b4.y, b4.z, b4.w};
    #pragma unroll
    for (int i = 0; i < 4; ++i) {
        float4 o;
        o.x = acc[i][0] + bb[0];
        o.y = acc[i][1] + bb[1];
        o.z = acc[i][2] + bb[2];
        o.w = acc[i][3] + bb[3];
        *reinterpret_cast<float4*>(&out[(size_t)(m0 + ty * 4 + i) * 3840 + n0 + tx * 4]) = o;
    }
}

// score[b,p,c,a] = sum_h tanh(hp[b,p,c,h] + ha[b,a,c,h]) * w_out[h]  + mask bias
__global__ __launch_bounds__(256) void scores_kernel(
    const float* __restrict__ hp,    // [320, 3840]
    const float* __restrict__ ha,    // [320, 3840]
    const float* __restrict__ w_out, // [768]
    const int*  __restrict__ mask,   // [B,S,C,S] as int32
    float* __restrict__ out)         // [B,S,C,S]
{
    const int at = blockIdx.x;       // 0..9
    const int pt = blockIdx.y;       // 0..9
    const int bc = blockIdx.z;       // 0..9
    const int b = bc / 5, c = bc % 5;

    const int tid = threadIdx.x;
    const int tp = tid >> 4, ta = tid & 15;

    __shared__ __attribute__((aligned(16))) float w_s[768];
    __shared__ __attribute__((aligned(16))) float hp_s[16][260]; // 256 + 4 pad
    __shared__ __attribute__((aligned(16))) float ha_s[16][260];

    if (tid < 192) {
        *reinterpret_cast<float4*>(&w_s[tid * 4]) =
            *reinterpret_cast<const float4*>(&w_out[tid * 4]);
    }

    const float* hp_base = hp + (size_t)(b * 160 + pt * 16) * 3840 + c * 768;
    const float* ha_base = ha + (size_t)(b * 160 + at * 16) * 3840 + c * 768;

    float acc = 0.f;

    for (int k0 = 0; k0 < 768; k0 += 256) {
        __syncthreads();   // protects w_s (iter 0) and hp_s/ha_s reuse (iters 1,2)
        #pragma unroll
        for (int i = 0; i < 4; ++i) {
            int f4  = i * 256 + tid;       // 0..1023
            int row = f4 >> 6;             // 16 rows, 64 float4 each
            int col = (f4 & 63) * 4;
            *reinterpret_cast<float4*>(&hp_s[row][col]) =
                *reinterpret_cast<const float4*>(&hp_base[(size_t)row * 3840 + k0 + col]);
            *reinterpret_cast<float4*>(&ha_s[row][col]) =
                *reinterpret_cast<const float4*>(&ha_base[(size_t)row * 3840 + k0 + col]);
        }
        __syncthreads();
        #pragma unroll 4
        for (int j = 0; j < 64; ++j) {
            float4 p4 = *reinterpret_cast<const float4*>(&hp_s[tp][j * 4]);
            float4 a4 = *reinterpret_cast<const float4*>(&ha_s[ta][j * 4]);
            float4 w4 = *reinterpret_cast<const float4*>(&w_s[k0 + j * 4]);
            acc = fmaf(fast_tanh(p4.x + a4.x), w4.x, acc);
            acc = fmaf(fast_tanh(p4.y + a4.y), w4.y, acc);
            acc = fmaf(fast_tanh(p4.z + a4.z), w4.z, acc);
            acc = fmaf(fast_tanh(p4.w + a4.w), w4.w, acc);
        }
    }

    const int p = pt * 16 + tp;
    const int a = at * 16 + ta;
    const size_t idx = ((size_t)(b * 160 + p) * 5 + c) * 160 + a;
    out[idx] = acc + (mask[idx] ? 0.f : -1024.f);
}

// one wave per (b,p,c) row of 160 args
__global__ __launch_bounds__(256) void loss_kernel(
    const float* __restrict__ scores,  // [1600,160]
    const int*  __restrict__ target,
    float* __restrict__ acc)           // acc[0]=sum(-logsm*t), acc[1]=sum(t)
{
    const int lane = threadIdx.x & 63;
    const int wid  = threadIdx.x >> 6;
    const int row  = blockIdx.x * 4 + wid;  // 0..1599
    const float* x = scores + (size_t)row * 160;
    const int*  t  = target + (size_t)row * 160;

    float x0 = x[lane];
    float x1 = x[lane + 64];
    float x2 = (lane < 32) ? x[lane + 128] : -INFINITY;

    float m = fmaxf(fmaxf(x0, x1), x2);
    #pragma unroll
    for (int o = 32; o >= 1; o >>= 1)
        m = fmaxf(m, __shfl_xor(m, o));

    float s = __expf(x0 - m) + __expf(x1 - m) + ((lane < 32) ? __expf(x2 - m) : 0.f);
    #pragma unroll
    for (int o = 32; o >= 1; o >>= 1)
        s += __shfl_xor(s, o);
    float lse = logf(s) + m;

    int t0 = t[lane], t1 = t[lane + 64];
    int t2 = (lane < 32) ? t[lane + 128] : 0;
    float pl = (float)t0 * (lse - x0) + (float)t1 * (lse - x1)
             + ((lane < 32 && t2) ? (float)t2 * (lse - x2) : 0.f);
    float pts = (float)(t0 + t1 + t2);
    #pragma unroll
    for (int o = 32; o >= 1; o >>= 1) {
        pl  += __shfl_xor(pl, o);
        pts += __shfl_xor(pts, o);
    }
    if (lane == 0) {
        atomicAdd(&acc[0], pl);
        atomicAdd(&acc[1], pts);
    }
}

__global__ void finalize_kernel(const float* __restrict__ acc, float* __restrict__ out0)
{
    out0[0] = acc[0] / (acc[1] + 1e-6f);
}

extern "C" void kernel_launch(void* const* d_in, const int* in_sizes, int n_in,
                              void* d_out, int out_size, void* d_ws, size_t ws_size,
                              hipStream_t stream) {
    const float* seq   = (const float*)d_in[0];
    const float* w_prd = (const float*)d_in[1];
    const float* b_prd = (const float*)d_in[2];
    const float* w_arg = (const float*)d_in[3];
    const float* b_arg = (const float*)d_in[4];
    const float* w_out = (const float*)d_in[5];
    const int*   mask  = (const int*)d_in[6];
    const int*   targ  = (const int*)d_in[7];

    float* out = (float*)d_out;          // out[0]=loss, out+1 = scores [2,160,5,160]
    float* hp  = (float*)d_ws;           // [320,3840]
    float* ha  = hp + 320 * 3840;        // [320,3840]
    float* acc = ha + 320 * 3840;        // [2]

    hipMemsetAsync(acc, 0, 2 * sizeof(float), stream);

    dim3 g1(60, 5, 2);   // N/64, M/64, {prd,arg}
    proj_gemm<<<g1, 256, 0, stream>>>(seq, w_prd, b_prd, w_arg, b_arg, hp, ha);

    dim3 g2(10, 10, 10); // a-tiles, p-tiles, b*c
    scores_kernel<<<g2, 256, 0, stream>>>(hp, ha, w_out, mask, out + 1);

    loss_kernel<<<400, 256, 0, stream>>>(out + 1, targ, acc);
    finalize_kernel<<<1, 1, 0, stream>>>(acc, out);
}

// Round 3
// 135.032 us; speedup vs baseline: 1.8787x; 1.3478x over previous
//
#include <hip/hip_runtime.h>
#include <hip/hip_bf16.h>
#include <math.h>

// B=2, S=160, H=768, C=5 ; M = B*S = 320, N = C*H = 3840, K = H = 768

typedef __attribute__((ext_vector_type(8))) short bf16x8;
typedef __attribute__((ext_vector_type(4))) float f32x4;

__device__ __forceinline__ unsigned short f2bf(float f) {
    union { float f; unsigned u; } v; v.f = f;
    unsigned r = (v.u + 0x7FFFu + ((v.u >> 16) & 1u)) >> 16;
    return (unsigned short)r;
}

__device__ __forceinline__ float fast_tanh(float x) {
    // clamp to [-4,4]; odd Pade (945+105x^2+x^4)/(945+420x^2+15x^4), err <~2e-3
    x = __builtin_amdgcn_fmed3f(x, -4.0f, 4.0f);
    float x2  = x * x;
    float num = x * fmaf(x2, x2 + 105.f, 945.f);
    float den = fmaf(x2, fmaf(x2, 15.f, 420.f), 945.f);
    return num * __builtin_amdgcn_rcpf(den);
}

// 64x64 output tile per block, BK=32, 4 waves each computing a 32x32 quadrant
// via 2x2 fragments of v_mfma_f32_16x16x32_bf16. fp32->bf16 conversion fused
// into LDS staging; W is transposed during staging so both operands are
// contiguous-in-K ds_read_b128.
__global__ __launch_bounds__(256) void proj_gemm_mfma(
    const float* __restrict__ A,     // [320, 768]
    const float* __restrict__ Wp,    // [768, 3840]
    const float* __restrict__ bp,    // [3840]
    const float* __restrict__ Wa,
    const float* __restrict__ ba,
    float* __restrict__ hp,          // [320, 3840]
    float* __restrict__ ha)
{
    const int which = blockIdx.z;
    const float* W    = which ? Wa : Wp;
    const float* bias = which ? ba : bp;
    float* out        = which ? ha : hp;

    const int n0 = blockIdx.x * 64;
    const int m0 = blockIdx.y * 64;
    const int tid  = threadIdx.x;
    const int lane = tid & 63;
    const int w    = tid >> 6;

    __shared__ __attribute__((aligned(16))) short As[64][40]; // [m][k], pad 32->40
    __shared__ __attribute__((aligned(16))) short Bs[64][40]; // [n][k] (W transposed)

    f32x4 acc[2][2] = {};

    // staging indices
    const int ra = tid >> 2;          // 0..63 : A row
    const int ka = (tid & 3) * 8;     // 0,8,16,24 : A k-offset
    const int nb = tid & 63;          // 0..63 : B col (n), lane-contiguous
    const int kb = (tid >> 6) * 8;    // 0,8,16,24 : B k-offset

    // fragment indices
    const int wm = (w & 1) * 32;
    const int wn = (w >> 1) * 32;
    const int fr = lane & 15;
    const int fk = (lane >> 4) * 8;

    const float* Arow = A + (size_t)(m0 + ra) * 768 + ka;

    for (int k0 = 0; k0 < 768; k0 += 32) {
        // issue global loads early (in flight across the barrier)
        float4 a0 = *reinterpret_cast<const float4*>(Arow + k0);
        float4 a1 = *reinterpret_cast<const float4*>(Arow + k0 + 4);
        float bvals[8];
        #pragma unroll
        for (int j = 0; j < 8; ++j)
            bvals[j] = W[(size_t)(k0 + kb + j) * 3840 + n0 + nb];

        __syncthreads();  // previous iteration's fragment reads complete

        bf16x8 av;
        av[0] = f2bf(a0.x); av[1] = f2bf(a0.y); av[2] = f2bf(a0.z); av[3] = f2bf(a0.w);
        av[4] = f2bf(a1.x); av[5] = f2bf(a1.y); av[6] = f2bf(a1.z); av[7] = f2bf(a1.w);
        *reinterpret_cast<bf16x8*>(&As[ra][ka]) = av;

        bf16x8 bv;
        #pragma unroll
        for (int j = 0; j < 8; ++j) bv[j] = f2bf(bvals[j]);
        *reinterpret_cast<bf16x8*>(&Bs[nb][kb]) = bv;

        __syncthreads();

        bf16x8 af0 = *reinterpret_cast<const bf16x8*>(&As[wm + fr][fk]);
        bf16x8 af1 = *reinterpret_cast<const bf16x8*>(&As[wm + 16 + fr][fk]);
        bf16x8 bf0 = *reinterpret_cast<const bf16x8*>(&Bs[wn + fr][fk]);
        bf16x8 bf1 = *reinterpret_cast<const bf16x8*>(&Bs[wn + 16 + fr][fk]);

        acc[0][0] = __builtin_amdgcn_mfma_f32_16x16x32_bf16(af0, bf0, acc[0][0], 0, 0, 0);
        acc[0][1] = __builtin_amdgcn_mfma_f32_16x16x32_bf16(af0, bf1, acc[0][1], 0, 0, 0);
        acc[1][0] = __builtin_amdgcn_mfma_f32_16x16x32_bf16(af1, bf0, acc[1][0], 0, 0, 0);
        acc[1][1] = __builtin_amdgcn_mfma_f32_16x16x32_bf16(af1, bf1, acc[1][1], 0, 0, 0);
    }

    // C/D layout: col = lane&15, row = (lane>>4)*4 + reg
    #pragma unroll
    for (int j = 0; j < 2; ++j) {
        const int col = n0 + wn + j * 16 + fr;
        const float bb = bias[col];
        #pragma unroll
        for (int i = 0; i < 2; ++i) {
            #pragma unroll
            for (int r = 0; r < 4; ++r) {
                const int row = m0 + wm + i * 16 + (lane >> 4) * 4 + r;
                out[(size_t)row * 3840 + col] = acc[i][j][r] + bb;
            }
        }
    }
}

// score[b,p,c,a] = sum_h tanh(hp[b,p,c,h] + ha[b,a,c,h]) * w_out[h]  + mask bias
__global__ __launch_bounds__(256) void scores_kernel(
    const float* __restrict__ hp,    // [320, 3840]
    const float* __restrict__ ha,    // [320, 3840]
    const float* __restrict__ w_out, // [768]
    const int*  __restrict__ mask,   // [B,S,C,S] as int32
    float* __restrict__ out)         // [B,S,C,S]
{
    const int at = blockIdx.x;       // 0..9
    const int pt = blockIdx.y;       // 0..9
    const int bc = blockIdx.z;       // 0..9
    const int b = bc / 5, c = bc % 5;

    const int tid = threadIdx.x;
    const int tp = tid >> 4, ta = tid & 15;

    __shared__ __attribute__((aligned(16))) float w_s[768];
    __shared__ __attribute__((aligned(16))) float hp_s[16][260]; // 256 + 4 pad
    __shared__ __attribute__((aligned(16))) float ha_s[16][260];

    if (tid < 192) {
        *reinterpret_cast<float4*>(&w_s[tid * 4]) =
            *reinterpret_cast<const float4*>(&w_out[tid * 4]);
    }

    const float* hp_base = hp + (size_t)(b * 160 + pt * 16) * 3840 + c * 768;
    const float* ha_base = ha + (size_t)(b * 160 + at * 16) * 3840 + c * 768;

    float acc = 0.f;

    for (int k0 = 0; k0 < 768; k0 += 256) {
        __syncthreads();   // protects w_s (iter 0) and hp_s/ha_s reuse (iters 1,2)
        #pragma unroll
        for (int i = 0; i < 4; ++i) {
            int f4  = i * 256 + tid;       // 0..1023
            int row = f4 >> 6;             // 16 rows, 64 float4 each
            int col = (f4 & 63) * 4;
            *reinterpret_cast<float4*>(&hp_s[row][col]) =
                *reinterpret_cast<const float4*>(&hp_base[(size_t)row * 3840 + k0 + col]);
            *reinterpret_cast<float4*>(&ha_s[row][col]) =
                *reinterpret_cast<const float4*>(&ha_base[(size_t)row * 3840 + k0 + col]);
        }
        __syncthreads();
        #pragma unroll 4
        for (int j = 0; j < 64; ++j) {
            float4 p4 = *reinterpret_cast<const float4*>(&hp_s[tp][j * 4]);
            float4 a4 = *reinterpret_cast<const float4*>(&ha_s[ta][j * 4]);
            float4 w4 = *reinterpret_cast<const float4*>(&w_s[k0 + j * 4]);
            acc = fmaf(fast_tanh(p4.x + a4.x), w4.x, acc);
            acc = fmaf(fast_tanh(p4.y + a4.y), w4.y, acc);
            acc = fmaf(fast_tanh(p4.z + a4.z), w4.z, acc);
            acc = fmaf(fast_tanh(p4.w + a4.w), w4.w, acc);
        }
    }

    const int p = pt * 16 + tp;
    const int a = at * 16 + ta;
    const size_t idx = ((size_t)(b * 160 + p) * 5 + c) * 160 + a;
    out[idx] = acc + (mask[idx] ? 0.f : -1024.f);
}

// one wave per (b,p,c) row of 160 args
__global__ __launch_bounds__(256) void loss_kernel(
    const float* __restrict__ scores,  // [1600,160]
    const int*  __restrict__ target,
    float* __restrict__ acc)           // acc[0]=sum(-logsm*t), acc[1]=sum(t)
{
    const int lane = threadIdx.x & 63;
    const int wid  = threadIdx.x >> 6;
    const int row  = blockIdx.x * 4 + wid;  // 0..1599
    const float* x = scores + (size_t)row * 160;
    const int*  t  = target + (size_t)row * 160;

    float x0 = x[lane];
    float x1 = x[lane + 64];
    float x2 = (lane < 32) ? x[lane + 128] : -INFINITY;

    float m = fmaxf(fmaxf(x0, x1), x2);
    #pragma unroll
    for (int o = 32; o >= 1; o >>= 1)
        m = fmaxf(m, __shfl_xor(m, o));

    float s = __expf(x0 - m) + __expf(x1 - m) + ((lane < 32) ? __expf(x2 - m) : 0.f);
    #pragma unroll
    for (int o = 32; o >= 1; o >>= 1)
        s += __shfl_xor(s, o);
    float lse = logf(s) + m;

    int t0 = t[lane], t1 = t[lane + 64];
    int t2 = (lane < 32) ? t[lane + 128] : 0;
    float pl = (float)t0 * (lse - x0) + (float)t1 * (lse - x1)
             + ((lane < 32 && t2) ? (float)t2 * (lse - x2) : 0.f);
    float pts = (float)(t0 + t1 + t2);
    #pragma unroll
    for (int o = 32; o >= 1; o >>= 1) {
        pl  += __shfl_xor(pl, o);
        pts += __shfl_xor(pts, o);
    }
    if (lane == 0) {
        atomicAdd(&acc[0], pl);
        atomicAdd(&acc[1], pts);
    }
}

__global__ void finalize_kernel(const float* __restrict__ acc, float* __restrict__ out0)
{
    out0[0] = acc[0] / (acc[1] + 1e-6f);
}

extern "C" void kernel_launch(void* const* d_in, const int* in_sizes, int n_in,
                              void* d_out, int out_size, void* d_ws, size_t ws_size,
                              hipStream_t stream) {
    const float* seq   = (const float*)d_in[0];
    const float* w_prd = (const float*)d_in[1];
    const float* b_prd = (const float*)d_in[2];
    const float* w_arg = (const float*)d_in[3];
    const float* b_arg = (const float*)d_in[4];
    const float* w_out = (const float*)d_in[5];
    const int*   mask  = (const int*)d_in[6];
    const int*   targ  = (const int*)d_in[7];

    float* out = (float*)d_out;          // out[0]=loss, out+1 = scores [2,160,5,160]
    float* hp  = (float*)d_ws;           // [320,3840]
    float* ha  = hp + 320 * 3840;        // [320,3840]
    float* acc = ha + 320 * 3840;        // [2]

    hipMemsetAsync(acc, 0, 2 * sizeof(float), stream);

    dim3 g1(60, 5, 2);   // N/64, M/64, {prd,arg}
    proj_gemm_mfma<<<g1, 256, 0, stream>>>(seq, w_prd, b_prd, w_arg, b_arg, hp, ha);

    dim3 g2(10, 10, 10); // a-tiles, p-tiles, b*c
    scores_kernel<<<g2, 256, 0, stream>>>(hp, ha, w_out, mask, out + 1);

    loss_kernel<<<400, 256, 0, stream>>>(out + 1, targ, acc);
    finalize_kernel<<<1, 1, 0, stream>>>(acc, out);
}

// Round 4
// 113.115 us; speedup vs baseline: 2.2427x; 1.1938x over previous
//
#include <hip/hip_runtime.h>
#include <hip/hip_bf16.h>
#include <math.h>

// B=2, S=160, H=768, C=5 ; M = B*S = 320, N = C*H = 3840, K = H = 768

typedef __attribute__((ext_vector_type(8))) short bf16x8;
typedef __attribute__((ext_vector_type(4))) float f32x4;

__device__ __forceinline__ unsigned short f2bf(float f) {
    union { float f; unsigned u; } v; v.f = f;
    unsigned r = (v.u + 0x7FFFu + ((v.u >> 16) & 1u)) >> 16;
    return (unsigned short)r;
}

// 64x64 output tile per block, BK=32, 4 waves each computing a 32x32 quadrant
// via v_mfma_f32_16x16x32_bf16. Epilogue stores tanh(acc+bias), clamped to
// +-0.999999 so the downstream tanh-addition identity is NaN-safe.
__global__ __launch_bounds__(256) void proj_gemm_mfma(
    const float* __restrict__ A,     // [320, 768]
    const float* __restrict__ Wp,    // [768, 3840]
    const float* __restrict__ bp,    // [3840]
    const float* __restrict__ Wa,
    const float* __restrict__ ba,
    float* __restrict__ hp,          // [320, 3840]  (tanh of projection)
    float* __restrict__ ha)
{
    const int which = blockIdx.z;
    const float* W    = which ? Wa : Wp;
    const float* bias = which ? ba : bp;
    float* out        = which ? ha : hp;

    const int n0 = blockIdx.x * 64;
    const int m0 = blockIdx.y * 64;
    const int tid  = threadIdx.x;
    const int lane = tid & 63;
    const int w    = tid >> 6;

    __shared__ __attribute__((aligned(16))) short As[64][40]; // [m][k], pad 32->40
    __shared__ __attribute__((aligned(16))) short Bs[64][40]; // [n][k] (W transposed)

    f32x4 acc[2][2] = {};

    // staging indices
    const int ra = tid >> 2;          // 0..63 : A row
    const int ka = (tid & 3) * 8;     // 0,8,16,24 : A k-offset
    const int nb = tid & 63;          // 0..63 : B col (n), lane-contiguous
    const int kb = (tid >> 6) * 8;    // 0,8,16,24 : B k-offset

    // fragment indices
    const int wm = (w & 1) * 32;
    const int wn = (w >> 1) * 32;
    const int fr = lane & 15;
    const int fk = (lane >> 4) * 8;

    const float* Arow = A + (size_t)(m0 + ra) * 768 + ka;

    for (int k0 = 0; k0 < 768; k0 += 32) {
        // issue global loads early (in flight across the barrier)
        float4 a0 = *reinterpret_cast<const float4*>(Arow + k0);
        float4 a1 = *reinterpret_cast<const float4*>(Arow + k0 + 4);
        float bvals[8];
        #pragma unroll
        for (int j = 0; j < 8; ++j)
            bvals[j] = W[(size_t)(k0 + kb + j) * 3840 + n0 + nb];

        __syncthreads();  // previous iteration's fragment reads complete

        bf16x8 av;
        av[0] = f2bf(a0.x); av[1] = f2bf(a0.y); av[2] = f2bf(a0.z); av[3] = f2bf(a0.w);
        av[4] = f2bf(a1.x); av[5] = f2bf(a1.y); av[6] = f2bf(a1.z); av[7] = f2bf(a1.w);
        *reinterpret_cast<bf16x8*>(&As[ra][ka]) = av;

        bf16x8 bv;
        #pragma unroll
        for (int j = 0; j < 8; ++j) bv[j] = f2bf(bvals[j]);
        *reinterpret_cast<bf16x8*>(&Bs[nb][kb]) = bv;

        __syncthreads();

        bf16x8 af0 = *reinterpret_cast<const bf16x8*>(&As[wm + fr][fk]);
        bf16x8 af1 = *reinterpret_cast<const bf16x8*>(&As[wm + 16 + fr][fk]);
        bf16x8 bf0 = *reinterpret_cast<const bf16x8*>(&Bs[wn + fr][fk]);
        bf16x8 bf1 = *reinterpret_cast<const bf16x8*>(&Bs[wn + 16 + fr][fk]);

        acc[0][0] = __builtin_amdgcn_mfma_f32_16x16x32_bf16(af0, bf0, acc[0][0], 0, 0, 0);
        acc[0][1] = __builtin_amdgcn_mfma_f32_16x16x32_bf16(af0, bf1, acc[0][1], 0, 0, 0);
        acc[1][0] = __builtin_amdgcn_mfma_f32_16x16x32_bf16(af1, bf0, acc[1][0], 0, 0, 0);
        acc[1][1] = __builtin_amdgcn_mfma_f32_16x16x32_bf16(af1, bf1, acc[1][1], 0, 0, 0);
    }

    // C/D layout: col = lane&15, row = (lane>>4)*4 + reg
    #pragma unroll
    for (int j = 0; j < 2; ++j) {
        const int col = n0 + wn + j * 16 + fr;
        const float bb = bias[col];
        #pragma unroll
        for (int i = 0; i < 2; ++i) {
            #pragma unroll
            for (int r = 0; r < 4; ++r) {
                const int row = m0 + wm + i * 16 + (lane >> 4) * 4 + r;
                float t = tanhf(acc[i][j][r] + bb);
                t = __builtin_amdgcn_fmed3f(t, -0.999999f, 0.999999f);
                out[(size_t)row * 3840 + col] = t;
            }
        }
    }
}

// score[b,p,c,a] = sum_h tanh(hp+ha)*w = sum_h ((tp+ta)/(1+tp*ta))*w  (exact identity)
__global__ __launch_bounds__(256) void scores_kernel(
    const float* __restrict__ tp_g,  // [320, 3840]  tanh(hp)
    const float* __restrict__ ta_g,  // [320, 3840]  tanh(ha)
    const float* __restrict__ w_out, // [768]
    const int*  __restrict__ mask,   // [B,S,C,S] as int32
    float* __restrict__ out)         // [B,S,C,S]
{
    const int at = blockIdx.x;       // 0..9
    const int pt = blockIdx.y;       // 0..9
    const int bc = blockIdx.z;       // 0..9
    const int b = bc / 5, c = bc % 5;

    const int tid = threadIdx.x;
    const int tp = tid >> 4, ta = tid & 15;

    __shared__ __attribute__((aligned(16))) float w_s[768];
    __shared__ __attribute__((aligned(16))) float hp_s[16][260]; // 256 + 4 pad
    __shared__ __attribute__((aligned(16))) float ha_s[16][260];

    if (tid < 192) {
        *reinterpret_cast<float4*>(&w_s[tid * 4]) =
            *reinterpret_cast<const float4*>(&w_out[tid * 4]);
    }

    const float* hp_base = tp_g + (size_t)(b * 160 + pt * 16) * 3840 + c * 768;
    const float* ha_base = ta_g + (size_t)(b * 160 + at * 16) * 3840 + c * 768;

    float acc = 0.f;

    for (int k0 = 0; k0 < 768; k0 += 256) {
        __syncthreads();   // protects w_s (iter 0) and hp_s/ha_s reuse (iters 1,2)
        #pragma unroll
        for (int i = 0; i < 4; ++i) {
            int f4  = i * 256 + tid;       // 0..1023
            int row = f4 >> 6;             // 16 rows, 64 float4 each
            int col = (f4 & 63) * 4;
            *reinterpret_cast<float4*>(&hp_s[row][col]) =
                *reinterpret_cast<const float4*>(&hp_base[(size_t)row * 3840 + k0 + col]);
            *reinterpret_cast<float4*>(&ha_s[row][col]) =
                *reinterpret_cast<const float4*>(&ha_base[(size_t)row * 3840 + k0 + col]);
        }
        __syncthreads();
        #pragma unroll 4
        for (int j = 0; j < 64; ++j) {
            float4 p4 = *reinterpret_cast<const float4*>(&hp_s[tp][j * 4]);
            float4 a4 = *reinterpret_cast<const float4*>(&ha_s[ta][j * 4]);
            float4 w4 = *reinterpret_cast<const float4*>(&w_s[k0 + j * 4]);
            {
                float s = p4.x + a4.x;
                float d = fmaf(p4.x, a4.x, 1.f);
                acc = fmaf(s * __builtin_amdgcn_rcpf(d), w4.x, acc);
            }
            {
                float s = p4.y + a4.y;
                float d = fmaf(p4.y, a4.y, 1.f);
                acc = fmaf(s * __builtin_amdgcn_rcpf(d), w4.y, acc);
            }
            {
                float s = p4.z + a4.z;
                float d = fmaf(p4.z, a4.z, 1.f);
                acc = fmaf(s * __builtin_amdgcn_rcpf(d), w4.z, acc);
            }
            {
                float s = p4.w + a4.w;
                float d = fmaf(p4.w, a4.w, 1.f);
                acc = fmaf(s * __builtin_amdgcn_rcpf(d), w4.w, acc);
            }
        }
    }

    const int p = pt * 16 + tp;
    const int a = at * 16 + ta;
    const size_t idx = ((size_t)(b * 160 + p) * 5 + c) * 160 + a;
    out[idx] = acc + (mask[idx] ? 0.f : -1024.f);
}

// one wave per (b,p,c) row of 160 args
__global__ __launch_bounds__(256) void loss_kernel(
    const float* __restrict__ scores,  // [1600,160]
    const int*  __restrict__ target,
    float* __restrict__ acc)           // acc[0]=sum(-logsm*t), acc[1]=sum(t)
{
    const int lane = threadIdx.x & 63;
    const int wid  = threadIdx.x >> 6;
    const int row  = blockIdx.x * 4 + wid;  // 0..1599
    const float* x = scores + (size_t)row * 160;
    const int*  t  = target + (size_t)row * 160;

    float x0 = x[lane];
    float x1 = x[lane + 64];
    float x2 = (lane < 32) ? x[lane + 128] : -INFINITY;

    float m = fmaxf(fmaxf(x0, x1), x2);
    #pragma unroll
    for (int o = 32; o >= 1; o >>= 1)
        m = fmaxf(m, __shfl_xor(m, o));

    float s = __expf(x0 - m) + __expf(x1 - m) + ((lane < 32) ? __expf(x2 - m) : 0.f);
    #pragma unroll
    for (int o = 32; o >= 1; o >>= 1)
        s += __shfl_xor(s, o);
    float lse = logf(s) + m;

    int t0 = t[lane], t1 = t[lane + 64];
    int t2 = (lane < 32) ? t[lane + 128] : 0;
    float pl = (float)t0 * (lse - x0) + (float)t1 * (lse - x1)
             + ((lane < 32 && t2) ? (float)t2 * (lse - x2) : 0.f);
    float pts = (float)(t0 + t1 + t2);
    #pragma unroll
    for (int o = 32; o >= 1; o >>= 1) {
        pl  += __shfl_xor(pl, o);
        pts += __shfl_xor(pts, o);
    }
    if (lane == 0) {
        atomicAdd(&acc[0], pl);
        atomicAdd(&acc[1], pts);
    }
}

__global__ void finalize_kernel(const float* __restrict__ acc, float* __restrict__ out0)
{
    out0[0] = acc[0] / (acc[1] + 1e-6f);
}

extern "C" void kernel_launch(void* const* d_in, const int* in_sizes, int n_in,
                              void* d_out, int out_size, void* d_ws, size_t ws_size,
                              hipStream_t stream) {
    const float* seq   = (const float*)d_in[0];
    const float* w_prd = (const float*)d_in[1];
    const float* b_prd = (const float*)d_in[2];
    const float* w_arg = (const float*)d_in[3];
    const float* b_arg = (const float*)d_in[4];
    const float* w_out = (const float*)d_in[5];
    const int*   mask  = (const int*)d_in[6];
    const int*   targ  = (const int*)d_in[7];

    float* out = (float*)d_out;          // out[0]=loss, out+1 = scores [2,160,5,160]
    float* hp  = (float*)d_ws;           // [320,3840]  tanh(h_p)
    float* ha  = hp + 320 * 3840;        // [320,3840]  tanh(h_a)
    float* acc = ha + 320 * 3840;        // [2]

    hipMemsetAsync(acc, 0, 2 * sizeof(float), stream);

    dim3 g1(60, 5, 2);   // N/64, M/64, {prd,arg}
    proj_gemm_mfma<<<g1, 256, 0, stream>>>(seq, w_prd, b_prd, w_arg, b_arg, hp, ha);

    dim3 g2(10, 10, 10); // a-tiles, p-tiles, b*c
    scores_kernel<<<g2, 256, 0, stream>>>(hp, ha, w_out, mask, out + 1);

    loss_kernel<<<400, 256, 0, stream>>>(out + 1, targ, acc);
    finalize_kernel<<<1, 1, 0, stream>>>(acc, out);
}